// Round 3
// baseline (523.727 us; speedup 1.0000x reference)
//
#include <hip/hip_runtime.h>

#define T_ 1024
#define H_ 2048
#define I_ 3200
#define E_ 8

typedef float fvec4 __attribute__((ext_vector_type(4)));
typedef float f32x4 __attribute__((ext_vector_type(4)));
typedef __bf16 bf16x8 __attribute__((ext_vector_type(8)));
typedef unsigned short u16x4 __attribute__((ext_vector_type(4)));

// ---- ws layout (bytes) ----
#define WS_TOK   128
#define WS_GATE  32896
#define WS_XB    65664
#define WS_ACT   4259968   // 3328 rows x 3200 bf16 (slack rows for OOB-safe A reads)

#define BAR() do { asm volatile("s_waitcnt lgkmcnt(0)" ::: "memory"); \
    __builtin_amdgcn_sched_barrier(0); __builtin_amdgcn_s_barrier(); } while (0)

// ---------------- router + sparsemixer + list build + x->bf16 ----------------
__global__ __launch_bounds__(256) void router_kernel(const float* __restrict__ x,
                                                     const float* __restrict__ gw,
                                                     int* __restrict__ cnt,
                                                     int* __restrict__ tok,
                                                     float* __restrict__ gate,
                                                     unsigned short* __restrict__ xb) {
  const int lane = threadIdx.x & 63;
  const int wv = threadIdx.x >> 6;
  const int t = blockIdx.x * 4 + wv;

  const float* xp = x + (size_t)t * H_;
  fvec4 xr[8];
#pragma unroll
  for (int j = 0; j < 8; ++j) xr[j] = *(const fvec4*)(xp + j * 256 + lane * 4);

  // fused x -> bf16
  unsigned short* xbp = xb + (size_t)t * H_;
#pragma unroll
  for (int j = 0; j < 8; ++j) {
    u16x4 o;
#pragma unroll
    for (int c = 0; c < 4; ++c) o[c] = __builtin_bit_cast(unsigned short, (__bf16)xr[j][c]);
    *(u16x4*)(xbp + j * 256 + lane * 4) = o;
  }

  float s[E_];
#pragma unroll
  for (int e = 0; e < E_; ++e) {
    const float* gp = gw + (size_t)e * H_;
    float p = 0.f;
#pragma unroll
    for (int j = 0; j < 8; ++j) {
      fvec4 g = *(const fvec4*)(gp + j * 256 + lane * 4);
      p = fmaf(xr[j][0], g[0], p); p = fmaf(xr[j][1], g[1], p);
      p = fmaf(xr[j][2], g[2], p); p = fmaf(xr[j][3], g[3], p);
    }
#pragma unroll
    for (int off = 32; off > 0; off >>= 1) p += __shfl_xor(p, off);
    s[e] = p;
  }

  float max1 = s[0]; int i1 = 0;
#pragma unroll
  for (int e = 1; e < E_; ++e) if (s[e] > max1) { max1 = s[e]; i1 = e; }
  float den1 = 0.f;
#pragma unroll
  for (int e = 0; e < E_; ++e) {
    float factor = fmaxf(fabsf(s[e]), max1);
    if ((max1 - s[e]) <= 0.02f * factor) den1 += expf(s[e] - max1);
  }
  float mult1 = 1.f / den1;

  float max2 = -INFINITY; int i2 = 0;
#pragma unroll
  for (int e = 0; e < E_; ++e) if (e != i1 && s[e] > max2) { max2 = s[e]; i2 = e; }
  float den2 = 0.f;
#pragma unroll
  for (int e = 0; e < E_; ++e) {
    if (e == i1) continue;
    float factor = fmaxf(fabsf(s[e]), max2);
    if ((max2 - s[e]) <= 0.02f * factor) den2 += expf(s[e] - max2);
  }
  float mult2 = 1.f / den2;

  if (lane == 0) {
    int p1 = atomicAdd(&cnt[i1], 1); tok[i1 * T_ + p1] = t; gate[i1 * T_ + p1] = mult1;
    int p2 = atomicAdd(&cnt[i2], 1); tok[i2 * T_ + p2] = t; gate[i2 * T_ + p2] = mult2;
  }
}

// ---------------- prefix of 128-padded counts ----------------
__global__ void prefix_kernel(const int* __restrict__ cnt, int* __restrict__ base) {
  if (threadIdx.x == 0 && blockIdx.x == 0) {
    int a = 0;
    for (int e = 0; e < E_; ++e) { base[e] = a; a += (cnt[e] + 127) & ~127; }
    base[E_] = a;
  }
}

// ---------------- FFN1: BM=256, BN=64, BK=64, 8 waves, A-in-regs, B dbuf LDS ----------------
__global__ __launch_bounds__(512, 2) void ffn1_kernel(
    const unsigned short* __restrict__ xb, const float* __restrict__ w1,
    const float* __restrict__ w3, const int* __restrict__ cnt,
    const int* __restrict__ base, const int* __restrict__ tokl,
    unsigned short* __restrict__ actb) {
  const int e = blockIdx.z;
  const int ab = base[e];
  const int padcnt = base[e + 1] - ab;
  const int m_base = blockIdx.y * 256;
  if (m_base >= padcnt) return;
  const int count = cnt[e];
  const int n0 = blockIdx.x * 64;
  const int tid = threadIdx.x;
  const int lane = tid & 63, wv = tid >> 6;
  const int wm = wv >> 1, wn = wv & 1;      // 4m x 2n waves; per-wave 64x32 out

  __shared__ unsigned short B1s[2][64 * 64];  // 16 KiB
  __shared__ unsigned short B3s[2][64 * 64];  // 16 KiB

  // A row pointers (per-lane gather, clamped)
  const unsigned short* aPtr[4];
#pragma unroll
  for (int mi = 0; mi < 4; ++mi) {
    int r = m_base + wm * 64 + mi * 16 + (lane & 15);
    if (r >= count) r = count - 1;
    aPtr[mi] = xb + (size_t)tokl[e * T_ + r] * H_ + (lane >> 4) * 8;
  }
  // B tile: 64 rows (I) x 64 cols (K) f32; thread: row=tid>>3, colgrp=tid&7
  const int brow = tid >> 3;
  const float* b1p = w1 + ((size_t)e * I_ + n0 + brow) * H_ + (tid & 7) * 8;
  const float* b3p = w3 + ((size_t)e * I_ + n0 + brow) * H_ + (tid & 7) * 8;
  const int wbyte = brow * 128 + (((tid & 7) ^ (brow & 7)) << 4);  // swizzled write

  int rb[2][2];   // ds_read byte offsets [ni][kk]
#pragma unroll
  for (int ni = 0; ni < 2; ++ni) {
    int br_ = wn * 32 + ni * 16 + (lane & 15);
#pragma unroll
    for (int kk = 0; kk < 2; ++kk)
      rb[ni][kk] = br_ * 128 + (((kk * 4 + (lane >> 4)) ^ (br_ & 7)) << 4);
  }

  f32x4 acc1[4][2], acc3[4][2];
#pragma unroll
  for (int mi = 0; mi < 4; ++mi)
#pragma unroll
    for (int ni = 0; ni < 2; ++ni) { acc1[mi][ni] = (f32x4){0,0,0,0}; acc3[mi][ni] = (f32x4){0,0,0,0}; }

  bf16x8 aA[4][2], aB[4][2];
  fvec4 b1e[2], b3e[2], b1o[2], b3o[2];

  auto LOADA = [&](bf16x8 (&as)[4][2], int kb) {
#pragma unroll
    for (int mi = 0; mi < 4; ++mi) {
      as[mi][0] = *(const bf16x8*)(aPtr[mi] + kb);
      as[mi][1] = *(const bf16x8*)(aPtr[mi] + kb + 32);
    }
  };
  auto LOADB = [&](fvec4 (&r1)[2], fvec4 (&r3)[2], int kb) {
    r1[0] = *(const fvec4*)(b1p + kb); r1[1] = *(const fvec4*)(b1p + kb + 4);
    r3[0] = *(const fvec4*)(b3p + kb); r3[1] = *(const fvec4*)(b3p + kb + 4);
  };
  auto CVTW = [&](fvec4 (&r1)[2], fvec4 (&r3)[2], int buf) {
    bf16x8 v, w;
#pragma unroll
    for (int c = 0; c < 4; ++c) {
      v[c] = (__bf16)r1[0][c]; v[c + 4] = (__bf16)r1[1][c];
      w[c] = (__bf16)r3[0][c]; w[c + 4] = (__bf16)r3[1][c];
    }
    *(bf16x8*)((char*)B1s[buf] + wbyte) = v;
    *(bf16x8*)((char*)B3s[buf] + wbyte) = w;
  };
  auto COMPUTE = [&](bf16x8 (&as)[4][2], int buf) {
    __builtin_amdgcn_s_setprio(1);
#pragma unroll
    for (int kk = 0; kk < 2; ++kk) {
      bf16x8 f1[2], f3[2];
#pragma unroll
      for (int ni = 0; ni < 2; ++ni) {
        f1[ni] = *(const bf16x8*)((const char*)B1s[buf] + rb[ni][kk]);
        f3[ni] = *(const bf16x8*)((const char*)B3s[buf] + rb[ni][kk]);
      }
#pragma unroll
      for (int mi = 0; mi < 4; ++mi)
#pragma unroll
        for (int ni = 0; ni < 2; ++ni) {
          acc1[mi][ni] = __builtin_amdgcn_mfma_f32_16x16x32_bf16(as[mi][kk], f1[ni], acc1[mi][ni], 0, 0, 0);
          acc3[mi][ni] = __builtin_amdgcn_mfma_f32_16x16x32_bf16(as[mi][kk], f3[ni], acc3[mi][ni], 0, 0, 0);
        }
    }
    __builtin_amdgcn_s_setprio(0);
  };

  const int NT = H_ / 64;  // 32, even
  LOADB(b1e, b3e, 0);
  LOADA(aA, 0);
  CVTW(b1e, b3e, 0);       // waits B[0] regs only (counted)
  LOADB(b1o, b3o, 64);     // B[1] in flight
  BAR();
  for (int t = 0; t < NT; t += 2) {
    // even body: compute tile t from buf0/aA
    LOADA(aB, (t + 1) * 64);
    if (t + 2 < NT) LOADB(b1e, b3e, (t + 2) * 64);
    COMPUTE(aA, 0);
    CVTW(b1o, b3o, 1);     // B[t+1] -> buf1
    BAR();
    // odd body: tile t+1 from buf1/aB
    if (t + 2 < NT) LOADA(aA, (t + 2) * 64);
    if (t + 3 < NT) LOADB(b1o, b3o, (t + 3) * 64);
    COMPUTE(aB, 1);
    if (t + 2 < NT) CVTW(b1e, b3e, 0);  // B[t+2] -> buf0
    BAR();
  }

  const int row_lim = padcnt - m_base;
#pragma unroll
  for (int mi = 0; mi < 4; ++mi)
#pragma unroll
    for (int ni = 0; ni < 2; ++ni)
#pragma unroll
      for (int j = 0; j < 4; ++j) {
        int row = wm * 64 + mi * 16 + (lane >> 4) * 4 + j;
        if (row < row_lim) {
          float h1 = acc1[mi][ni][j];
          float a = (h1 / (1.f + __expf(-h1))) * acc3[mi][ni][j];
          actb[(size_t)(ab + m_base + row) * I_ + n0 + wn * 32 + ni * 16 + (lane & 15)] =
              __builtin_bit_cast(unsigned short, (__bf16)a);
        }
      }
}

// ---------------- FFN2: BM=256, BN=64, BK=64, same pipeline, single B ----------------
__global__ __launch_bounds__(512, 2) void ffn2_kernel(
    const unsigned short* __restrict__ actb, const float* __restrict__ w2,
    const int* __restrict__ cnt, const int* __restrict__ base,
    const int* __restrict__ tokl, const float* __restrict__ gatel,
    float* __restrict__ out) {
  const int e = blockIdx.z;
  const int count = cnt[e];
  const int m_base = blockIdx.y * 256;
  if (m_base >= count) return;
  const int ab = base[e];
  const int n0 = blockIdx.x * 64;
  const int tid = threadIdx.x;
  const int lane = tid & 63, wv = tid >> 6;
  const int wm = wv >> 1, wn = wv & 1;

  __shared__ unsigned short Bs[2][64 * 64];   // 16 KiB

  const unsigned short* aPtr[4];
#pragma unroll
  for (int mi = 0; mi < 4; ++mi) {
    int r = ab + m_base + wm * 64 + mi * 16 + (lane & 15);
    aPtr[mi] = actb + (size_t)r * I_ + (lane >> 4) * 8;   // slack rows are finite garbage
  }
  const int brow = tid >> 3;
  const float* bp = w2 + ((size_t)e * H_ + n0 + brow) * I_ + (tid & 7) * 8;
  const int wbyte = brow * 128 + (((tid & 7) ^ (brow & 7)) << 4);

  int rb[2][2];
#pragma unroll
  for (int ni = 0; ni < 2; ++ni) {
    int br_ = wn * 32 + ni * 16 + (lane & 15);
#pragma unroll
    for (int kk = 0; kk < 2; ++kk)
      rb[ni][kk] = br_ * 128 + (((kk * 4 + (lane >> 4)) ^ (br_ & 7)) << 4);
  }

  f32x4 acc[4][2];
#pragma unroll
  for (int mi = 0; mi < 4; ++mi)
#pragma unroll
    for (int ni = 0; ni < 2; ++ni) acc[mi][ni] = (f32x4){0,0,0,0};

  bf16x8 aA[4][2], aB[4][2];
  fvec4 be[2], bo[2];

  auto LOADA = [&](bf16x8 (&as)[4][2], int kb) {
#pragma unroll
    for (int mi = 0; mi < 4; ++mi) {
      as[mi][0] = *(const bf16x8*)(aPtr[mi] + kb);
      as[mi][1] = *(const bf16x8*)(aPtr[mi] + kb + 32);
    }
  };
  auto LOADB = [&](fvec4 (&r)[2], int kb) {
    r[0] = *(const fvec4*)(bp + kb); r[1] = *(const fvec4*)(bp + kb + 4);
  };
  auto CVTW = [&](fvec4 (&r)[2], int buf) {
    bf16x8 v;
#pragma unroll
    for (int c = 0; c < 4; ++c) { v[c] = (__bf16)r[0][c]; v[c + 4] = (__bf16)r[1][c]; }
    *(bf16x8*)((char*)Bs[buf] + wbyte) = v;
  };
  auto COMPUTE = [&](bf16x8 (&as)[4][2], int buf) {
    __builtin_amdgcn_s_setprio(1);
#pragma unroll
    for (int kk = 0; kk < 2; ++kk) {
      bf16x8 f[2];
#pragma unroll
      for (int ni = 0; ni < 2; ++ni)
        f[ni] = *(const bf16x8*)((const char*)Bs[buf] + rb[ni][kk]);
#pragma unroll
      for (int mi = 0; mi < 4; ++mi)
#pragma unroll
        for (int ni = 0; ni < 2; ++ni)
          acc[mi][ni] = __builtin_amdgcn_mfma_f32_16x16x32_bf16(as[mi][kk], f[ni], acc[mi][ni], 0, 0, 0);
    }
    __builtin_amdgcn_s_setprio(0);
  };

  const int NT = I_ / 64;  // 50, even
  LOADB(be, 0);
  LOADA(aA, 0);
  CVTW(be, 0);
  LOADB(bo, 64);
  BAR();
  for (int t = 0; t < NT; t += 2) {
    LOADA(aB, (t + 1) * 64);
    if (t + 2 < NT) LOADB(be, (t + 2) * 64);
    COMPUTE(aA, 0);
    CVTW(bo, 1);
    BAR();
    if (t + 2 < NT) LOADA(aA, (t + 2) * 64);
    if (t + 3 < NT) LOADB(bo, (t + 3) * 64);
    COMPUTE(aB, 1);
    if (t + 2 < NT) CVTW(be, 0);
    BAR();
  }

#pragma unroll
  for (int mi = 0; mi < 4; ++mi)
#pragma unroll
    for (int j = 0; j < 4; ++j) {
      int row = m_base + wm * 64 + mi * 16 + (lane >> 4) * 4 + j;
      if (row < count) {
        int tokv = tokl[e * T_ + row];
        float g = gatel[e * T_ + row];
#pragma unroll
        for (int ni = 0; ni < 2; ++ni)
          atomicAdd(&out[(size_t)tokv * H_ + n0 + wn * 32 + ni * 16 + (lane & 15)],
                    g * acc[mi][ni][j]);
      }
    }
}

extern "C" void kernel_launch(void* const* d_in, const int* in_sizes, int n_in,
                              void* d_out, int out_size, void* d_ws, size_t ws_size,
                              hipStream_t stream) {
  const float* x  = (const float*)d_in[0];
  const float* gw = (const float*)d_in[1];
  const float* w1 = (const float*)d_in[2];
  const float* w3 = (const float*)d_in[3];
  const float* w2 = (const float*)d_in[4];
  float* out = (float*)d_out;
  char* ws = (char*)d_ws;

  int* cnt = (int*)ws;
  int* base = (int*)(ws + 64);
  int* tokl = (int*)(ws + WS_TOK);
  float* gatel = (float*)(ws + WS_GATE);
  unsigned short* xb = (unsigned short*)(ws + WS_XB);
  unsigned short* actb = (unsigned short*)(ws + WS_ACT);

  (void)hipMemsetAsync(d_out, 0, (size_t)T_ * H_ * sizeof(float), stream);
  (void)hipMemsetAsync(ws, 0, 64, stream);

  router_kernel<<<T_ / 4, 256, 0, stream>>>(x, gw, cnt, tokl, gatel, xb);
  prefix_kernel<<<1, 64, 0, stream>>>(cnt, base);
  ffn1_kernel<<<dim3(I_ / 64, 4, E_), 512, 0, stream>>>(xb, w1, w3, cnt, base, tokl, actb);
  ffn2_kernel<<<dim3(H_ / 64, 4, E_), 512, 0, stream>>>(actb, w2, cnt, base, tokl, gatel, out);
}

// Round 4
// 352.720 us; speedup vs baseline: 1.4848x; 1.4848x over previous
//
#include <hip/hip_runtime.h>

#define T_ 1024
#define H_ 2048
#define I_ 3200
#define E_ 8

typedef float fvec4 __attribute__((ext_vector_type(4)));
typedef float f32x4 __attribute__((ext_vector_type(4)));
typedef __bf16 bf16x8 __attribute__((ext_vector_type(8)));
typedef unsigned short u16x4 __attribute__((ext_vector_type(4)));

typedef const __attribute__((address_space(1))) void* gp1_t;
typedef __attribute__((address_space(3))) void* sp3_t;

// ---- ws layout (bytes) ----
#define WS_TOK   128
#define WS_GATE  32896
#define WS_XB    65664
#define WS_ACT   4259968   // 3328 rows x 3200 bf16 (slack rows for OOB-safe A reads)

#define BARX() { asm volatile("s_waitcnt lgkmcnt(0)" ::: "memory"); \
    __builtin_amdgcn_sched_barrier(0); __builtin_amdgcn_s_barrier(); }

// ---------------- router + sparsemixer + list build + x->bf16 ----------------
__global__ __launch_bounds__(256) void router_kernel(const float* __restrict__ x,
                                                     const float* __restrict__ gw,
                                                     int* __restrict__ cnt,
                                                     int* __restrict__ tok,
                                                     float* __restrict__ gate,
                                                     unsigned short* __restrict__ xb) {
  const int lane = threadIdx.x & 63;
  const int wv = threadIdx.x >> 6;
  const int t = blockIdx.x * 4 + wv;

  const float* xp = x + (size_t)t * H_;
  fvec4 xr[8];
#pragma unroll
  for (int j = 0; j < 8; ++j) xr[j] = *(const fvec4*)(xp + j * 256 + lane * 4);

  unsigned short* xbp = xb + (size_t)t * H_;
#pragma unroll
  for (int j = 0; j < 8; ++j) {
    u16x4 o;
#pragma unroll
    for (int c = 0; c < 4; ++c) o[c] = __builtin_bit_cast(unsigned short, (__bf16)xr[j][c]);
    *(u16x4*)(xbp + j * 256 + lane * 4) = o;
  }

  float s[E_];
#pragma unroll
  for (int e = 0; e < E_; ++e) {
    const float* gp = gw + (size_t)e * H_;
    float p = 0.f;
#pragma unroll
    for (int j = 0; j < 8; ++j) {
      fvec4 g = *(const fvec4*)(gp + j * 256 + lane * 4);
      p = fmaf(xr[j][0], g[0], p); p = fmaf(xr[j][1], g[1], p);
      p = fmaf(xr[j][2], g[2], p); p = fmaf(xr[j][3], g[3], p);
    }
#pragma unroll
    for (int off = 32; off > 0; off >>= 1) p += __shfl_xor(p, off);
    s[e] = p;
  }

  float max1 = s[0]; int i1 = 0;
#pragma unroll
  for (int e = 1; e < E_; ++e) if (s[e] > max1) { max1 = s[e]; i1 = e; }
  float den1 = 0.f;
#pragma unroll
  for (int e = 0; e < E_; ++e) {
    float factor = fmaxf(fabsf(s[e]), max1);
    if ((max1 - s[e]) <= 0.02f * factor) den1 += expf(s[e] - max1);
  }
  float mult1 = 1.f / den1;

  float max2 = -INFINITY; int i2 = 0;
#pragma unroll
  for (int e = 0; e < E_; ++e) if (e != i1 && s[e] > max2) { max2 = s[e]; i2 = e; }
  float den2 = 0.f;
#pragma unroll
  for (int e = 0; e < E_; ++e) {
    if (e == i1) continue;
    float factor = fmaxf(fabsf(s[e]), max2);
    if ((max2 - s[e]) <= 0.02f * factor) den2 += expf(s[e] - max2);
  }
  float mult2 = 1.f / den2;

  if (lane == 0) {
    int p1 = atomicAdd(&cnt[i1], 1); tok[i1 * T_ + p1] = t; gate[i1 * T_ + p1] = mult1;
    int p2 = atomicAdd(&cnt[i2], 1); tok[i2 * T_ + p2] = t; gate[i2 * T_ + p2] = mult2;
  }
}

// ---------------- prefix of 128-padded counts ----------------
__global__ void prefix_kernel(const int* __restrict__ cnt, int* __restrict__ base) {
  if (threadIdx.x == 0 && blockIdx.x == 0) {
    int a = 0;
    for (int e = 0; e < E_; ++e) { base[e] = a; a += (cnt[e] + 127) & ~127; }
    base[E_] = a;
  }
}

// ---------------- FFN1: BM=256, BN=64, BK=64, A 3-buf LDS, B 2-deep reg->LDS ----------------
__global__ __launch_bounds__(512, 2) void ffn1_kernel(
    const unsigned short* __restrict__ xb, const float* __restrict__ w1,
    const float* __restrict__ w3, const int* __restrict__ cnt,
    const int* __restrict__ base, const int* __restrict__ tokl,
    unsigned short* __restrict__ actb) {
  const int e = blockIdx.z;
  const int ab = base[e];
  const int padcnt = base[e + 1] - ab;
  const int m_base = blockIdx.y * 256;
  if (m_base >= padcnt) return;
  const int count = cnt[e];
  const int n0 = blockIdx.x * 64;
  const int tid = threadIdx.x;
  const int lane = tid & 63, wv = tid >> 6;   // 8 waves
  const int wm = wv >> 1, wn = wv & 1;        // 4m x 2n; per-wave 64x32 out

  __shared__ unsigned short Ash[3][256 * 64]; // 96 KiB, triple-buffered
  __shared__ unsigned short B1s[2][64 * 64];  // 16 KiB
  __shared__ unsigned short B3s[2][64 * 64];  // 16 KiB

  // A gather sources (coalesced glds; pre-swizzled global column)
  const unsigned short* aSrc[4];
  const int colg = ((lane & 7) ^ ((lane >> 3) & 7)) * 8;
#pragma unroll
  for (int i = 0; i < 4; ++i) {
    int r = m_base + wv * 32 + i * 8 + (lane >> 3);
    if (r >= count) r = count - 1;
    aSrc[i] = xb + (size_t)tokl[e * T_ + r] * H_ + colg;
  }
  const int brow = tid >> 3;
  const float* b1p = w1 + ((size_t)e * I_ + n0 + brow) * H_ + (tid & 7) * 8;
  const float* b3p = w3 + ((size_t)e * I_ + n0 + brow) * H_ + (tid & 7) * 8;
  const int wbyte = brow * 128 + (((tid & 7) ^ (brow & 7)) << 4);

  int rb[2][2];
#pragma unroll
  for (int ni = 0; ni < 2; ++ni) {
    int br_ = wn * 32 + ni * 16 + (lane & 15);
#pragma unroll
    for (int kk = 0; kk < 2; ++kk)
      rb[ni][kk] = br_ * 128 + (((kk * 4 + (lane >> 4)) ^ (br_ & 7)) << 4);
  }

  f32x4 acc1[4][2], acc3[4][2];
#pragma unroll
  for (int mi = 0; mi < 4; ++mi)
#pragma unroll
    for (int ni = 0; ni < 2; ++ni) { acc1[mi][ni] = (f32x4){0,0,0,0}; acc3[mi][ni] = (f32x4){0,0,0,0}; }

  auto STAGE_A = [&](unsigned short* dst, int kb) {
#pragma unroll
    for (int i = 0; i < 4; ++i)
      __builtin_amdgcn_global_load_lds((gp1_t)(aSrc[i] + kb),
                                       (sp3_t)(dst + (wv * 32 + i * 8) * 64), 16, 0, 0);
  };
  auto LOADB = [&](fvec4 (&r1)[2], fvec4 (&r3)[2], int kb) {
    r1[0] = *(const fvec4*)(b1p + kb); r1[1] = *(const fvec4*)(b1p + kb + 4);
    r3[0] = *(const fvec4*)(b3p + kb); r3[1] = *(const fvec4*)(b3p + kb + 4);
  };
  auto CVTW = [&](fvec4 (&r1)[2], fvec4 (&r3)[2], int buf) {
    bf16x8 v, w;
#pragma unroll
    for (int c = 0; c < 4; ++c) {
      v[c] = (__bf16)r1[0][c]; v[c + 4] = (__bf16)r1[1][c];
      w[c] = (__bf16)r3[0][c]; w[c + 4] = (__bf16)r3[1][c];
    }
    *(bf16x8*)((char*)B1s[buf] + wbyte) = v;
    *(bf16x8*)((char*)B3s[buf] + wbyte) = w;
  };
  auto FRAGA = [&](bf16x8 (&af)[4][2], const unsigned short* Ab) {
#pragma unroll
    for (int mi = 0; mi < 4; ++mi) {
      int ar = wm * 64 + mi * 16 + (lane & 15);
#pragma unroll
      for (int kk = 0; kk < 2; ++kk)
        af[mi][kk] = *(const bf16x8*)((const char*)Ab + ar * 128 +
                                      (((kk * 4 + (lane >> 4)) ^ (ar & 7)) << 4));
    }
  };
  auto COMPUTE = [&](bf16x8 (&af)[4][2], int buf) {
    __builtin_amdgcn_s_setprio(1);
#pragma unroll
    for (int kk = 0; kk < 2; ++kk) {
      bf16x8 f1[2], f3[2];
#pragma unroll
      for (int ni = 0; ni < 2; ++ni) {
        f1[ni] = *(const bf16x8*)((const char*)B1s[buf] + rb[ni][kk]);
        f3[ni] = *(const bf16x8*)((const char*)B3s[buf] + rb[ni][kk]);
      }
#pragma unroll
      for (int mi = 0; mi < 4; ++mi)
#pragma unroll
        for (int ni = 0; ni < 2; ++ni) {
          acc1[mi][ni] = __builtin_amdgcn_mfma_f32_16x16x32_bf16(af[mi][kk], f1[ni], acc1[mi][ni], 0, 0, 0);
          acc3[mi][ni] = __builtin_amdgcn_mfma_f32_16x16x32_bf16(af[mi][kk], f3[ni], acc3[mi][ni], 0, 0, 0);
        }
    }
    __builtin_amdgcn_s_setprio(0);
  };

  const int NT = H_ / 64;  // 32 (even)
  unsigned short *A0 = Ash[0], *A1 = Ash[1], *A2 = Ash[2];
  fvec4 b1e[2], b3e[2], b1o[2], b3o[2];
  bf16x8 af[4][2];

  STAGE_A(A0, 0);
  LOADB(b1e, b3e, 0);
  STAGE_A(A1, 64);
  LOADB(b1o, b3o, 64);
  asm volatile("s_waitcnt vmcnt(8)" ::: "memory");   // tile0 A+B landed
  CVTW(b1e, b3e, 0);
  BARX();

  for (int t = 0; t < NT; t += 2) {
    // ---- even tile t: A in A0, B in buf0; A(t+1),B(t+1) in flight ----
    if (t + 2 < NT) { STAGE_A(A2, (t + 2) * 64); LOADB(b1e, b3e, (t + 2) * 64); }
    FRAGA(af, A0);
    COMPUTE(af, 0);
    if (t + 2 < NT) { asm volatile("s_waitcnt vmcnt(8)" ::: "memory"); }
    else            { asm volatile("s_waitcnt vmcnt(0)" ::: "memory"); }
    CVTW(b1o, b3o, 1);                 // B(t+1) -> buf1
    BARX();
    // ---- odd tile t+1: A in A1, B in buf1 ----
    if (t + 3 < NT) { STAGE_A(A0, (t + 3) * 64); LOADB(b1o, b3o, (t + 3) * 64); }
    FRAGA(af, A1);
    COMPUTE(af, 1);
    if (t + 2 < NT) {
      if (t + 3 < NT) { asm volatile("s_waitcnt vmcnt(8)" ::: "memory"); }
      else            { asm volatile("s_waitcnt vmcnt(0)" ::: "memory"); }
      CVTW(b1e, b3e, 0);               // B(t+2) -> buf0
    }
    BARX();
    unsigned short* tmp = A2; A2 = A1; A1 = A0; A0 = tmp;   // rotate
  }

  const int row_lim = padcnt - m_base;
#pragma unroll
  for (int mi = 0; mi < 4; ++mi)
#pragma unroll
    for (int ni = 0; ni < 2; ++ni)
#pragma unroll
      for (int j = 0; j < 4; ++j) {
        int row = wm * 64 + mi * 16 + (lane >> 4) * 4 + j;
        if (row < row_lim) {
          float h1 = acc1[mi][ni][j];
          float a = (h1 / (1.f + __expf(-h1))) * acc3[mi][ni][j];
          actb[(size_t)(ab + m_base + row) * I_ + n0 + wn * 32 + ni * 16 + (lane & 15)] =
              __builtin_bit_cast(unsigned short, (__bf16)a);
        }
      }
}

// ---------------- FFN2: same pipeline, single B matrix ----------------
__global__ __launch_bounds__(512, 2) void ffn2_kernel(
    const unsigned short* __restrict__ actb, const float* __restrict__ w2,
    const int* __restrict__ cnt, const int* __restrict__ base,
    const int* __restrict__ tokl, const float* __restrict__ gatel,
    float* __restrict__ out) {
  const int e = blockIdx.z;
  const int count = cnt[e];
  const int m_base = blockIdx.y * 256;
  if (m_base >= count) return;
  const int ab = base[e];
  const int n0 = blockIdx.x * 64;
  const int tid = threadIdx.x;
  const int lane = tid & 63, wv = tid >> 6;
  const int wm = wv >> 1, wn = wv & 1;

  __shared__ unsigned short Ash[3][256 * 64]; // 96 KiB
  __shared__ unsigned short Bs[2][64 * 64];   // 16 KiB

  const unsigned short* aSrc[4];
  const int colg = ((lane & 7) ^ ((lane >> 3) & 7)) * 8;
#pragma unroll
  for (int i = 0; i < 4; ++i) {
    int r = ab + m_base + wv * 32 + i * 8 + (lane >> 3);
    aSrc[i] = actb + (size_t)r * I_ + colg;
  }
  const int brow = tid >> 3;
  const float* bp = w2 + ((size_t)e * H_ + n0 + brow) * I_ + (tid & 7) * 8;
  const int wbyte = brow * 128 + (((tid & 7) ^ (brow & 7)) << 4);

  int rb[2][2];
#pragma unroll
  for (int ni = 0; ni < 2; ++ni) {
    int br_ = wn * 32 + ni * 16 + (lane & 15);
#pragma unroll
    for (int kk = 0; kk < 2; ++kk)
      rb[ni][kk] = br_ * 128 + (((kk * 4 + (lane >> 4)) ^ (br_ & 7)) << 4);
  }

  f32x4 acc[4][2];
#pragma unroll
  for (int mi = 0; mi < 4; ++mi)
#pragma unroll
    for (int ni = 0; ni < 2; ++ni) acc[mi][ni] = (f32x4){0,0,0,0};

  auto STAGE_A = [&](unsigned short* dst, int kb) {
#pragma unroll
    for (int i = 0; i < 4; ++i)
      __builtin_amdgcn_global_load_lds((gp1_t)(aSrc[i] + kb),
                                       (sp3_t)(dst + (wv * 32 + i * 8) * 64), 16, 0, 0);
  };
  auto LOADB = [&](fvec4 (&r)[2], int kb) {
    r[0] = *(const fvec4*)(bp + kb); r[1] = *(const fvec4*)(bp + kb + 4);
  };
  auto CVTW = [&](fvec4 (&r)[2], int buf) {
    bf16x8 v;
#pragma unroll
    for (int c = 0; c < 4; ++c) { v[c] = (__bf16)r[0][c]; v[c + 4] = (__bf16)r[1][c]; }
    *(bf16x8*)((char*)Bs[buf] + wbyte) = v;
  };
  auto FRAGA = [&](bf16x8 (&af)[4][2], const unsigned short* Ab) {
#pragma unroll
    for (int mi = 0; mi < 4; ++mi) {
      int ar = wm * 64 + mi * 16 + (lane & 15);
#pragma unroll
      for (int kk = 0; kk < 2; ++kk)
        af[mi][kk] = *(const bf16x8*)((const char*)Ab + ar * 128 +
                                      (((kk * 4 + (lane >> 4)) ^ (ar & 7)) << 4));
    }
  };
  auto COMPUTE = [&](bf16x8 (&af)[4][2], int buf) {
    __builtin_amdgcn_s_setprio(1);
#pragma unroll
    for (int kk = 0; kk < 2; ++kk) {
      bf16x8 f[2];
#pragma unroll
      for (int ni = 0; ni < 2; ++ni)
        f[ni] = *(const bf16x8*)((const char*)Bs[buf] + rb[ni][kk]);
#pragma unroll
      for (int mi = 0; mi < 4; ++mi)
#pragma unroll
        for (int ni = 0; ni < 2; ++ni)
          acc[mi][ni] = __builtin_amdgcn_mfma_f32_16x16x32_bf16(af[mi][kk], f[ni], acc[mi][ni], 0, 0, 0);
    }
    __builtin_amdgcn_s_setprio(0);
  };

  const int NT = I_ / 64;  // 50 (even)
  unsigned short *A0 = Ash[0], *A1 = Ash[1], *A2 = Ash[2];
  fvec4 be[2], bo[2];
  bf16x8 af[4][2];

  STAGE_A(A0, 0);
  LOADB(be, 0);
  STAGE_A(A1, 64);
  LOADB(bo, 64);
  asm volatile("s_waitcnt vmcnt(6)" ::: "memory");
  CVTW(be, 0);
  BARX();

  for (int t = 0; t < NT; t += 2) {
    if (t + 2 < NT) { STAGE_A(A2, (t + 2) * 64); LOADB(be, (t + 2) * 64); }
    FRAGA(af, A0);
    COMPUTE(af, 0);
    if (t + 2 < NT) { asm volatile("s_waitcnt vmcnt(6)" ::: "memory"); }
    else            { asm volatile("s_waitcnt vmcnt(0)" ::: "memory"); }
    CVTW(bo, 1);
    BARX();
    if (t + 3 < NT) { STAGE_A(A0, (t + 3) * 64); LOADB(bo, (t + 3) * 64); }
    FRAGA(af, A1);
    COMPUTE(af, 1);
    if (t + 2 < NT) {
      if (t + 3 < NT) { asm volatile("s_waitcnt vmcnt(6)" ::: "memory"); }
      else            { asm volatile("s_waitcnt vmcnt(0)" ::: "memory"); }
      CVTW(be, 0);
    }
    BARX();
    unsigned short* tmp = A2; A2 = A1; A1 = A0; A0 = tmp;
  }

#pragma unroll
  for (int mi = 0; mi < 4; ++mi)
#pragma unroll
    for (int j = 0; j < 4; ++j) {
      int row = m_base + wm * 64 + mi * 16 + (lane >> 4) * 4 + j;
      if (row < count) {
        int tokv = tokl[e * T_ + row];
        float g = gatel[e * T_ + row];
#pragma unroll
        for (int ni = 0; ni < 2; ++ni)
          atomicAdd(&out[(size_t)tokv * H_ + n0 + wn * 32 + ni * 16 + (lane & 15)],
                    g * acc[mi][ni][j]);
      }
    }
}

extern "C" void kernel_launch(void* const* d_in, const int* in_sizes, int n_in,
                              void* d_out, int out_size, void* d_ws, size_t ws_size,
                              hipStream_t stream) {
  const float* x  = (const float*)d_in[0];
  const float* gw = (const float*)d_in[1];
  const float* w1 = (const float*)d_in[2];
  const float* w3 = (const float*)d_in[3];
  const float* w2 = (const float*)d_in[4];
  float* out = (float*)d_out;
  char* ws = (char*)d_ws;

  int* cnt = (int*)ws;
  int* base = (int*)(ws + 64);
  int* tokl = (int*)(ws + WS_TOK);
  float* gatel = (float*)(ws + WS_GATE);
  unsigned short* xb = (unsigned short*)(ws + WS_XB);
  unsigned short* actb = (unsigned short*)(ws + WS_ACT);

  (void)hipMemsetAsync(d_out, 0, (size_t)T_ * H_ * sizeof(float), stream);
  (void)hipMemsetAsync(ws, 0, 64, stream);

  router_kernel<<<T_ / 4, 256, 0, stream>>>(x, gw, cnt, tokl, gatel, xb);
  prefix_kernel<<<1, 64, 0, stream>>>(cnt, base);
  ffn1_kernel<<<dim3(I_ / 64, 4, E_), 512, 0, stream>>>(xb, w1, w3, cnt, base, tokl, actb);
  ffn2_kernel<<<dim3(H_ / 64, 4, E_), 512, 0, stream>>>(actb, w2, cnt, base, tokl, gatel, out);
}